// Round 2
// baseline (144.406 us; speedup 1.0000x reference)
//
#include <hip/hip_runtime.h>

// Problem constants (from reference): B=8, L=4096, D=2048, P=4, S=4, R=32
#define BB 8
#define LL 4096
#define DD 2048
#define PP 4
#define SS 4
#define RR 32

// Kernel 1: fp32 -> fp32 copy of the whole hidden tensor (float4 per lane-iter).
__global__ void copy_kernel(const float4* __restrict__ in,
                            float4* __restrict__ out,
                            long long n4) {
    long long idx = (long long)blockIdx.x * blockDim.x + threadIdx.x;
    long long stride = (long long)gridDim.x * blockDim.x;
    for (; idx < n4; idx += stride) {
        out[idx] = in[idx];
    }
}

// Kernel 2: compute the 64 adapted rows and overwrite them in out.
// One block per (b, n): n in [0,8) -> prefix rows 0..3, suffix rows seqlen-4..seqlen-1.
// 256 threads; thread t owns columns i = t*8 .. t*8+7.
__global__ __launch_bounds__(256) void adapt_kernel(
    const float* __restrict__ hidden,
    const float* __restrict__ proj_w,   // [8][2048][32]
    const float* __restrict__ src_w,    // [8][2048][32]
    const float* __restrict__ src_bias, // [32]
    const int*   __restrict__ seqlens,  // [8]
    float* __restrict__ out)
{
    const int b = blockIdx.x >> 3;
    const int n = blockIdx.x & 7;
    const int row = (n < PP) ? n : (seqlens[b] - SS + (n - PP));

    const float* x  = hidden + ((size_t)b * LL + row) * DD;
    const float* wp = proj_w + (size_t)n * DD * RR;
    const float* ws = src_w  + (size_t)n * DD * RR;

    const int tid = threadIdx.x;
    const int i0  = tid * 8;

    // Load this thread's 8 row elements
    float xv[8];
    {
        const float4* px = (const float4*)(x + i0);
        float4 a = px[0], c = px[1];
        xv[0] = a.x; xv[1] = a.y; xv[2] = a.z; xv[3] = a.w;
        xv[4] = c.x; xv[5] = c.y; xv[6] = c.z; xv[7] = c.w;
    }

    // Partial dot products over this thread's i-slice, for all 32 outputs
    float pP[RR], pS[RR];
#pragma unroll
    for (int o = 0; o < RR; ++o) { pP[o] = 0.f; pS[o] = 0.f; }

#pragma unroll
    for (int k = 0; k < 8; ++k) {
        const float4* wpr = (const float4*)(wp + (size_t)(i0 + k) * RR);
        const float4* wsr = (const float4*)(ws + (size_t)(i0 + k) * RR);
        const float xi = xv[k];
#pragma unroll
        for (int q = 0; q < 8; ++q) {
            float4 a = wpr[q];
            pP[q*4+0] += xi * a.x; pP[q*4+1] += xi * a.y;
            pP[q*4+2] += xi * a.z; pP[q*4+3] += xi * a.w;
            float4 s = wsr[q];
            pS[q*4+0] += xi * s.x; pS[q*4+1] += xi * s.y;
            pS[q*4+2] += xi * s.z; pS[q*4+3] += xi * s.w;
        }
    }

    // Reduce across the 64-lane wave (lane 0 gets wave total)
#pragma unroll
    for (int off = 32; off >= 1; off >>= 1) {
#pragma unroll
        for (int o = 0; o < RR; ++o) {
            pP[o] += __shfl_down(pP[o], off);
            pS[o] += __shfl_down(pS[o], off);
        }
    }

    // Cross-wave reduce through LDS (4 waves of 64)
    __shared__ float ldsP[4][RR];
    __shared__ float ldsS[4][RR];
    __shared__ float delta[RR];
    const int wave = tid >> 6;
    const int lane = tid & 63;
    if (lane == 0) {
#pragma unroll
        for (int o = 0; o < RR; ++o) { ldsP[wave][o] = pP[o]; ldsS[wave][o] = pS[o]; }
    }
    __syncthreads();
    if (tid < RR) {
        float sp = ldsP[0][tid] + ldsP[1][tid] + ldsP[2][tid] + ldsP[3][tid];
        float ss = ldsS[0][tid] + ldsS[1][tid] + ldsS[2][tid] + ldsS[3][tid] + src_bias[tid];
        ss = ss > 0.f ? ss : 0.f;              // relu(source)
        delta[tid] = ss - sp;                  // source - projected
    }
    __syncthreads();

    float dl[RR];
#pragma unroll
    for (int o = 0; o < RR; ++o) dl[o] = delta[o];

    // adapted_out[i] = x[i] + sum_o delta[o] * proj_w[n][i][o]; store as fp32
    float* orow = out + ((size_t)b * LL + row) * DD;
    float res[8];
#pragma unroll
    for (int k = 0; k < 8; ++k) {
        const float4* wpr = (const float4*)(wp + (size_t)(i0 + k) * RR);
        float acc = xv[k];
#pragma unroll
        for (int q = 0; q < 8; ++q) {
            float4 a = wpr[q];
            acc += dl[q*4+0] * a.x + dl[q*4+1] * a.y
                 + dl[q*4+2] * a.z + dl[q*4+3] * a.w;
        }
        res[k] = acc;
    }
    ((float4*)(orow + i0))[0] = make_float4(res[0], res[1], res[2], res[3]);
    ((float4*)(orow + i0))[1] = make_float4(res[4], res[5], res[6], res[7]);
}

extern "C" void kernel_launch(void* const* d_in, const int* in_sizes, int n_in,
                              void* d_out, int out_size, void* d_ws, size_t ws_size,
                              hipStream_t stream) {
    const float* hidden   = (const float*)d_in[0];
    const float* proj_w   = (const float*)d_in[1];
    const float* src_w    = (const float*)d_in[2];
    const float* src_bias = (const float*)d_in[3];
    const int*   seqlens  = (const int*)d_in[4];
    float* out            = (float*)d_out;

    const long long n4 = (long long)BB * LL * DD / 4;   // 16.78M float4s
    copy_kernel<<<2048, 256, 0, stream>>>((const float4*)hidden, (float4*)out, n4);
    adapt_kernel<<<BB * (PP + SS), 256, 0, stream>>>(hidden, proj_w, src_w,
                                                     src_bias, seqlens, out);
}